// Round 5
// baseline (402.254 us; speedup 1.0000x reference)
//
#include <hip/hip_runtime.h>

// LSS voxel pooling: N_POINTS=692736, C=64, B=4, NX=256, NY=256, NZ=1 (gz==0)
// final[b, c, 0, ix, iy] = sum over points at (ix,iy,b) of x[:, c]
// out flat: ((b*64 + c)*256 + ix)*256 + iy   (fp32, 64 MB)
//
// Strategy: one-pass fixed-capacity binning (transposed slot array, cheap
// L2 atomics on a 1 MB cursor), then register gather-sum with 2-point
// unrolling, writing directly in the final [B,C,X,Y] layout.

#define NPTS   692736          // = 2706 * 256 exactly
#define CFEAT  64
#define NXV    256
#define NYV    256
#define NBAT   4
#define NVOX   (NBAT * NXV * NYV)   // 262144
#define CAP    24               // >= max points/voxel for this data (~13);
                                // overflow list keeps correctness regardless

typedef float v4f __attribute__((ext_vector_type(4)));  // clang-native for nt builtins

// ws layout (bytes):
//   [0,    1 MB)   cursor[NVOX]        (memset 0 each call)
//   [1 MB, +4 B)   novf                (memset 0 each call, same memset)
//   [2 MB, 26 MB)  slots[CAP][NVOX]    (transposed: slots[pos*NVOX + v])
//   [32 MB, +5.5M) ovf int2[NPTS]      (full capacity -> always correct)

__global__ __launch_bounds__(256) void fill_slots_kernel(
    const int* __restrict__ geom, int* __restrict__ cursor,
    int* __restrict__ slots, int* __restrict__ novf, int2* __restrict__ ovf)
{
    int i = blockIdx.x * 256 + threadIdx.x;          // grid exact: 2706*256
    const int4 g = *(const int4*)(geom + (size_t)i * 4);  // gx, gy, gz(=0), gb
    int v = (g.w * NXV + g.x) * NYV + g.y;
    int pos = atomicAdd(&cursor[v], 1);
    if (pos < CAP) {
        slots[pos * NVOX + v] = i;
    } else {
        int o = atomicAdd(novf, 1);
        ovf[o] = make_int2(v, i);
    }
}

// Block = (b, ix); 512 threads = 256 iy x 2 channel-halves (32 ch each).
// Slot reads: slots[j*NVOX + v] -> consecutive v across lanes (coalesced).
// x reads: each (lane, half) reads exactly one 128 B line per point (nt).
// Writes: per channel, 256 lanes hit consecutive iy -> 1 KB bursts (nt).
__global__ __launch_bounds__(512) void gather_kernel(
    const float* __restrict__ x, const int* __restrict__ cursor,
    const int* __restrict__ slots, const int* __restrict__ novf,
    const int2* __restrict__ ovf, float* __restrict__ out)
{
    int b  = blockIdx.x >> 8;
    int ix = blockIdx.x & 255;
    int iy = threadIdx.x & 255;
    int h  = threadIdx.x >> 8;           // channel half: c in [h*32, h*32+32)

    int v = (b * NXV + ix) * NYV + iy;
    int cnt = cursor[v];
    if (cnt > CAP) cnt = CAP;

    v4f acc[8] = {};
    int j = 0;
    for (; j + 2 <= cnt; j += 2) {
        int p0 = slots[j * NVOX + v];
        int p1 = slots[(j + 1) * NVOX + v];
        const v4f* r0 = (const v4f*)(x + (size_t)p0 * CFEAT + h * 32);
        const v4f* r1 = (const v4f*)(x + (size_t)p1 * CFEAT + h * 32);
        v4f f0[8], f1[8];
        #pragma unroll
        for (int q = 0; q < 8; ++q) f0[q] = __builtin_nontemporal_load(&r0[q]);
        #pragma unroll
        for (int q = 0; q < 8; ++q) f1[q] = __builtin_nontemporal_load(&r1[q]);
        #pragma unroll
        for (int q = 0; q < 8; ++q) acc[q] += f0[q] + f1[q];
    }
    if (j < cnt) {
        int p0 = slots[j * NVOX + v];
        const v4f* r0 = (const v4f*)(x + (size_t)p0 * CFEAT + h * 32);
        #pragma unroll
        for (int q = 0; q < 8; ++q) acc[q] += __builtin_nontemporal_load(&r0[q]);
    }

    // overflow points (n is ~always 0 for this data; kept for correctness)
    int no = *novf;
    for (int t = 0; t < no; ++t) {
        int2 e = ovf[t];
        if (e.x == v) {
            const v4f* r0 = (const v4f*)(x + (size_t)e.y * CFEAT + h * 32);
            #pragma unroll
            for (int q = 0; q < 8; ++q) acc[q] += r0[q];
        }
    }

    size_t obase = (((size_t)b * CFEAT + h * 32) * NXV + ix) * NYV + iy;
    #pragma unroll
    for (int q = 0; q < 8; ++q) {
        __builtin_nontemporal_store(acc[q].x, &out[obase + (size_t)(q * 4 + 0) * (NXV * NYV)]);
        __builtin_nontemporal_store(acc[q].y, &out[obase + (size_t)(q * 4 + 1) * (NXV * NYV)]);
        __builtin_nontemporal_store(acc[q].z, &out[obase + (size_t)(q * 4 + 2) * (NXV * NYV)]);
        __builtin_nontemporal_store(acc[q].w, &out[obase + (size_t)(q * 4 + 3) * (NXV * NYV)]);
    }
}

extern "C" void kernel_launch(void* const* d_in, const int* in_sizes, int n_in,
                              void* d_out, int out_size, void* d_ws, size_t ws_size,
                              hipStream_t stream) {
    const float* x  = (const float*)d_in[0];   // fp32 [NPTS,64]
    const int* geom = (const int*)d_in[1];     // [NPTS,4]
    float* out      = (float*)d_out;           // fp32 [4,64,256,256]

    char* w = (char*)d_ws;
    int* cursor = (int*)(w);                       // 1 MB
    int* novf   = (int*)(w + (1u << 20));          // 4 B
    int* slots  = (int*)(w + (2u << 20));          // CAP * NVOX * 4 = 24 MB
    int2* ovf   = (int2*)(w + (32u << 20));        // NPTS * 8 B

    // zero cursor + novf in one memset (novf sits at the 1 MB boundary)
    (void)hipMemsetAsync(w, 0, (1u << 20) + 64, stream);

    fill_slots_kernel<<<NPTS / 256, 256, 0, stream>>>(geom, cursor, slots, novf, ovf);
    gather_kernel   <<<NBAT * NXV, 512, 0, stream>>>(x, cursor, slots, novf, ovf, out);
}